// Round 2
// baseline (2920.853 us; speedup 1.0000x reference)
//
#include <hip/hip_runtime.h>
#include <math.h>

// RelationalMemoryCell: B=2048, S=8, H=8, HS=128, M=1024, QKV=384, TOTAL=3072,
// IN_DIM=1024. All fp32.
//
// Pruning: m2[:, :-1] drops the s=8 (x) row => MLP rows + attention q-rows only
// for s=0..7. k/v need all 9 rows.
//
// Structure: x-GEMM + gi once; then the rest is independent per batch element,
// so it runs in chunks of Bc batches with chunk-sized scratch (qkv buffer for
// the full batch would be 226 MB — round-1 crash was d_ws overflow).

// ---------------------------------------------------------------------------
// Tiled fp32 GEMM: C[r][n] = sum_k opA(r,k) * W[k][n] + bias[n] (+res)(relu)
// BM=BN=64, BK=16, 256 threads, 4x4 micro-tile.
// a_mode 0: A row-major (lda=K). a_mode 1: gather mpi rows (chunk-local) from
// mem (9-row groups: rows 0..7 from mem, row 8 from x).
// ---------------------------------------------------------------------------
__global__ __launch_bounds__(256)
void gemm64(const float* __restrict__ A, const float* __restrict__ W,
            const float* __restrict__ bias, float* __restrict__ C,
            const float* __restrict__ res, int N, int K, int relu,
            int a_mode, const float* __restrict__ mem, const float* __restrict__ x)
{
    __shared__ __align__(16) float As[16][68];
    __shared__ __align__(16) float Bs[16][64];
    const int tid = threadIdx.x;
    const int tx = tid & 15, ty = tid >> 4;
    const int rowBase = blockIdx.y * 64;
    const int colBase = blockIdx.x * 64;

    float acc[4][4] = {};
    for (int k0 = 0; k0 < K; k0 += 16) {
        #pragma unroll
        for (int l = 0; l < 4; ++l) {
            int e  = tid + l * 256;
            int ar = e >> 4;      // 0..63
            int ak = e & 15;      // 0..15
            int r  = rowBase + ar;
            const float* aptr;
            if (a_mode == 0) {
                aptr = A + (size_t)r * K;
            } else {
                int b = r / 9, s = r - b * 9;   // chunk-local b
                aptr = (s < 8) ? (mem + (size_t)b * 8192 + (size_t)s * 1024)
                               : (x   + (size_t)b * 1024);
            }
            As[ak][ar] = aptr[k0 + ak];
        }
        #pragma unroll
        for (int l = 0; l < 4; ++l) {
            int e  = tid + l * 256;
            int bk = e >> 6;      // 0..15
            int bn = e & 63;      // 0..63
            Bs[bk][bn] = W[(size_t)(k0 + bk) * N + colBase + bn];
        }
        __syncthreads();
        #pragma unroll
        for (int k = 0; k < 16; ++k) {
            float4 a4 = *(const float4*)&As[k][ty * 4];
            float4 b4 = *(const float4*)&Bs[k][tx * 4];
            float av[4] = {a4.x, a4.y, a4.z, a4.w};
            float bv[4] = {b4.x, b4.y, b4.z, b4.w};
            #pragma unroll
            for (int i = 0; i < 4; ++i)
                #pragma unroll
                for (int j = 0; j < 4; ++j)
                    acc[i][j] += av[i] * bv[j];
        }
        __syncthreads();
    }
    #pragma unroll
    for (int i = 0; i < 4; ++i) {
        int r = rowBase + ty * 4 + i;
        #pragma unroll
        for (int j = 0; j < 4; ++j) {
            int c = colBase + tx * 4 + j;
            float v = acc[i][j] + bias[c];
            if (res) v += res[(size_t)r * N + c];
            if (relu) v = fmaxf(v, 0.f);
            C[(size_t)r * N + c] = v;
        }
    }
}

// ---------------------------------------------------------------------------
// Attention, chunk-local: one block per (b_local, h). Writes
// m1_c[(b_local*8+s)*1024 + h*128 + d] = mem_c[...] + att.
// ---------------------------------------------------------------------------
__global__ __launch_bounds__(128)
void attn_kernel(const float* __restrict__ qkv, const float* __restrict__ mem,
                 float* __restrict__ m1)
{
    const int bh = blockIdx.x;
    const int b = bh >> 3, h = bh & 7;       // chunk-local b
    __shared__ float qs[8][129];
    __shared__ float ks[9][129];
    __shared__ float vs[9][129];
    __shared__ float w[8][9];
    __shared__ float sred[8][9];
    const int tid = threadIdx.x;             // 128
    const float scale = 0.05103103630798288f;  // 384^-0.5

    #pragma unroll
    for (int s = 0; s < 9; ++s) {
        const float* base = qkv + (size_t)(b * 9 + s) * 3072 + h * 384;
        if (s < 8) qs[s][tid] = base[tid] * scale;
        ks[s][tid] = base[128 + tid];
        vs[s][tid] = base[256 + tid];
    }
    __syncthreads();

    if (tid < 72) {
        const int i = tid / 9, j = tid % 9;
        float sc = 0.f;
        #pragma unroll 8
        for (int d = 0; d < 128; ++d) sc += qs[i][d] * ks[j][d];
        sred[i][j] = sc;
    }
    __syncthreads();

    if (tid < 8) {
        float mx = -1e30f;
        for (int j2 = 0; j2 < 9; ++j2) mx = fmaxf(mx, sred[tid][j2]);
        float e[9], sum = 0.f;
        for (int j2 = 0; j2 < 9; ++j2) { e[j2] = expf(sred[tid][j2] - mx); sum += e[j2]; }
        float inv = 1.f / sum;
        for (int j2 = 0; j2 < 9; ++j2) w[tid][j2] = e[j2] * inv;
    }
    __syncthreads();

    #pragma unroll
    for (int i2 = 0; i2 < 8; ++i2) {
        float acc = 0.f;
        #pragma unroll
        for (int j2 = 0; j2 < 9; ++j2) acc += w[i2][j2] * vs[j2][tid];
        size_t off = (size_t)(b * 8 + i2) * 1024 + (size_t)h * 128 + tid;
        m1[off] = mem[off] + acc;
    }
}

// ---------------------------------------------------------------------------
// gi[b][g] = x[b,:] . kernel_gi[:,g] + bias_gi[g]   (global b, run once)
// ---------------------------------------------------------------------------
__global__ __launch_bounds__(256)
void gi_kernel(const float* __restrict__ x, const float* __restrict__ kgi,
               const float* __restrict__ bgi, float* __restrict__ gi)
{
    const int b = blockIdx.x, tid = threadIdx.x;
    float g0 = 0.f, g1 = 0.f;
    for (int k = tid; k < 1024; k += 256) {
        float xv = x[(size_t)b * 1024 + k];
        g0 += xv * kgi[k * 2];
        g1 += xv * kgi[k * 2 + 1];
    }
    __shared__ float r0[256], r1[256];
    r0[tid] = g0; r1[tid] = g1;
    __syncthreads();
    for (int s = 128; s > 0; s >>= 1) {
        if (tid < s) { r0[tid] += r0[tid + s]; r1[tid] += r1[tid + s]; }
        __syncthreads();
    }
    if (tid == 0) { gi[b * 2] = r0[0] + bgi[0]; gi[b * 2 + 1] = r1[0] + bgi[1]; }
}

// ---------------------------------------------------------------------------
// Final, chunk-local rows; gi passed pre-offset to the chunk (gi + b0*2).
// out = sigmoid(gm0+gi0)*tanh(m2) + sigmoid(gm1+gi1+1)*mem
// ---------------------------------------------------------------------------
__global__ __launch_bounds__(256)
void final_kernel(const float* __restrict__ mem, const float* __restrict__ m2,
                  const float* __restrict__ kgm, const float* __restrict__ bgm,
                  const float* __restrict__ gi, float* __restrict__ out)
{
    const int row = blockIdx.x;   // chunk-local b*8+s
    const int b = row >> 3;
    const int tid = threadIdx.x;
    const float* mrow = mem + (size_t)row * 1024;
    float g0 = 0.f, g1 = 0.f;
    for (int k = tid; k < 1024; k += 256) {
        float t = tanhf(mrow[k]);
        g0 += t * kgm[k * 2];
        g1 += t * kgm[k * 2 + 1];
    }
    __shared__ float r0[256], r1[256];
    r0[tid] = g0; r1[tid] = g1;
    __syncthreads();
    for (int s = 128; s > 0; s >>= 1) {
        if (tid < s) { r0[tid] += r0[tid + s]; r1[tid] += r1[tid + s]; }
        __syncthreads();
    }
    __shared__ float ig_s, fg_s;
    if (tid == 0) {
        float gate0 = r0[0] + bgm[0] + gi[b * 2];
        float gate1 = r1[0] + bgm[1] + gi[b * 2 + 1] + 1.0f;   // FORGET_BIAS
        ig_s = 1.f / (1.f + expf(-gate0));
        fg_s = 1.f / (1.f + expf(-gate1));
    }
    __syncthreads();
    const float ig = ig_s, fg = fg_s;
    const float* m2row = m2 + (size_t)row * 1024;
    float* orow = out + (size_t)row * 1024;
    for (int k = tid; k < 1024; k += 256)
        orow[k] = ig * tanhf(m2row[k]) + fg * mrow[k];
}

// ---------------------------------------------------------------------------
extern "C" void kernel_launch(void* const* d_in, const int* in_sizes, int n_in,
                              void* d_out, int out_size, void* d_ws, size_t ws_size,
                              hipStream_t stream)
{
    const float* inputs     = (const float*)d_in[0];
    const float* memory     = (const float*)d_in[1];
    const float* kernel_qkv = (const float*)d_in[2];
    const float* bias_qkv   = (const float*)d_in[3];
    const float* kernel_gi  = (const float*)d_in[4];
    const float* bias_gi    = (const float*)d_in[5];
    const float* kernel_gm  = (const float*)d_in[6];
    const float* bias_gm    = (const float*)d_in[7];
    const float* kernel_in  = (const float*)d_in[8];
    const float* bias_in    = (const float*)d_in[9];
    const float* mlp_k0     = (const float*)d_in[10];
    const float* mlp_b0     = (const float*)d_in[11];
    const float* mlp_k1     = (const float*)d_in[12];
    const float* mlp_b1     = (const float*)d_in[13];
    float* out = (float*)d_out;

    // ---- workspace layout (floats), chunk size chosen to fit ws_size ----
    float* ws_x  = (float*)d_ws;                      // 2048*1024
    float* ws_gi = ws_x + (size_t)2048 * 1024;        // 4096
    const size_t fixed_floats = (size_t)2048 * 1024 + 4096;

    // per-chunk floats: qkv Bc*9*3072  + m1 Bc*8*1024 + h Bc*8*1024
    int Bc = 64;
    for (int cand = 2048; cand >= 64; cand >>= 1) {
        size_t need = (fixed_floats + (size_t)cand * (9 * 3072 + 2 * 8 * 1024)) * 4;
        if (need <= ws_size) { Bc = cand; break; }
    }
    float* ws_qkv = ws_gi  + 4096;
    float* ws_m1  = ws_qkv + (size_t)Bc * 9 * 3072;
    float* ws_h   = ws_m1  + (size_t)Bc * 8 * 1024;

    dim3 blk(256);

    // x = inputs @ kernel_in + bias_in                  (2048 x 1024, K=1024)
    gemm64<<<dim3(1024 / 64, 2048 / 64), blk, 0, stream>>>(
        inputs, kernel_in, bias_in, ws_x, nullptr, 1024, 1024, 0, 0, nullptr, nullptr);

    // gi = x @ kernel_gi + bias_gi   (global, once)
    gi_kernel<<<2048, blk, 0, stream>>>(ws_x, kernel_gi, bias_gi, ws_gi);

    const int NC = 2048 / Bc;
    for (int c = 0; c < NC; ++c) {
        const int b0 = c * Bc;
        const float* mem_c = memory + (size_t)b0 * 8192;
        const float* x_c   = ws_x   + (size_t)b0 * 1024;

        // qkv_c = mpi_c @ kernel_qkv + bias_qkv         (Bc*9 x 3072, K=1024)
        gemm64<<<dim3(3072 / 64, Bc * 9 / 64), blk, 0, stream>>>(
            nullptr, kernel_qkv, bias_qkv, ws_qkv, nullptr, 3072, 1024, 0, 1, mem_c, x_c);

        // attention -> m1_c (rows s=0..7)
        attn_kernel<<<Bc * 8, dim3(128), 0, stream>>>(ws_qkv, mem_c, ws_m1);

        // h_c = relu(m1_c @ mlp_k0 + mlp_b0)            (Bc*8 x 1024, K=1024)
        gemm64<<<dim3(1024 / 64, Bc * 8 / 64), blk, 0, stream>>>(
            ws_m1, mlp_k0, mlp_b0, ws_h, nullptr, 1024, 1024, 1, 0, nullptr, nullptr);

        // m2_c = m1_c + h_c @ mlp_k1 + mlp_b1           (in-place into ws_m1)
        gemm64<<<dim3(1024 / 64, Bc * 8 / 64), blk, 0, stream>>>(
            ws_h, mlp_k1, mlp_b1, ws_m1, ws_m1, 1024, 1024, 0, 0, nullptr, nullptr);

        // gates + blend -> out chunk
        final_kernel<<<Bc * 8, blk, 0, stream>>>(
            mem_c, ws_m1, kernel_gm, bias_gm, ws_gi + (size_t)b0 * 2,
            out + (size_t)b0 * 8192);
    }
}

// Round 3
// 663.008 us; speedup vs baseline: 4.4055x; 4.4055x over previous
//
#include <hip/hip_runtime.h>
#include <math.h>

// RelationalMemoryCell: B=2048, S=8, H=8, M=1024, QKV=384, TOTAL=3072,
// IN_DIM=1024. fp32 in/out; GEMMs internally bf16 MFMA (fp32 accumulate).
//
// Pruning: m2[:, :-1] drops the s=8 row => MLP + attention q only for s=0..7.
//
// GEMM: 128x128 tile, BK=32, 256 thr = 4 waves (2x2), each wave 4x4 tiles of
// mfma_f32_16x16x32_bf16. A (MxK bf16) and Wt (NxK bf16) staged via
// global_load_lds width=16 into XOR-swizzled LDS (2-way banks = free).

typedef unsigned short ushort_t;                                  // bf16 bits
typedef short bf16x8_t __attribute__((ext_vector_type(8)));       // MFMA A/B frag
typedef float f32x4_t  __attribute__((ext_vector_type(4)));       // MFMA C/D frag

__device__ __forceinline__ ushort_t f2bf(float f) {               // RNE
    unsigned int u = __float_as_uint(f);
    u += 0x7fff + ((u >> 16) & 1);
    return (ushort_t)(u >> 16);
}
__device__ __forceinline__ float bf2f(ushort_t h) {
    return __uint_as_float(((unsigned int)h) << 16);
}

__device__ __forceinline__ void load_lds_16(const void* g, void* l) {
    __builtin_amdgcn_global_load_lds(
        (const __attribute__((address_space(1))) void*)g,
        (__attribute__((address_space(3))) void*)l, 16, 0, 0);
}

// ---------------------------------------------------------------------------
// bf16 MFMA GEMM. C[r][n] = sum_k A[r][k]*W[k][n] + bias[n] (+res)(relu).
// A: MxK bf16 row-major. Wt: NxK bf16 row-major (W pre-transposed).
// Outputs: Cf (fp32, optional) and/or Cb (bf16, optional). M,N multiples of 128,
// K multiple of 32.
// ---------------------------------------------------------------------------
__global__ __launch_bounds__(256)
void gemm_mfma(const ushort_t* __restrict__ A, const ushort_t* __restrict__ Wt,
               const float* __restrict__ bias, float* __restrict__ Cf,
               ushort_t* __restrict__ Cb, const float* __restrict__ res,
               int M, int N, int K, int relu)
{
    __shared__ __align__(16) ushort_t As[128 * 32];
    __shared__ __align__(16) ushort_t Bs[128 * 32];
    const int tid  = threadIdx.x;
    const int wave = tid >> 6, lane = tid & 63;
    const int wr = (wave >> 1) * 64;        // wave row offset in 128-tile
    const int wc = (wave & 1)  * 64;        // wave col offset
    const int lrow  = lane & 15;            // m (A) / n (B) / col (D)
    const int lquad = lane >> 4;            // k-group (A,B) / row-group (D)
    const int rowBase = blockIdx.y * 128;
    const int colBase = blockIdx.x * 128;

    f32x4_t acc[4][4] = {};

    for (int k0 = 0; k0 < K; k0 += 32) {
        // stage A and B tiles: 8192 B each = 512 x 16B granules = 2 issues
        #pragma unroll
        for (int i = 0; i < 2; ++i) {
            int e    = i * 256 + tid;
            int row  = e >> 2;                       // 0..127
            int c    = (e & 3) ^ ((row >> 1) & 3);   // swizzled k-chunk (8 elems)
            const ushort_t* ga = A  + (size_t)(rowBase + row) * K + k0 + c * 8;
            const ushort_t* gb = Wt + (size_t)(colBase + row) * K + k0 + c * 8;
            load_lds_16(ga, &As[e * 8]);
            load_lds_16(gb, &Bs[e * 8]);
        }
        __syncthreads();

        bf16x8_t af[4], bfr[4];
        #pragma unroll
        for (int t = 0; t < 4; ++t) {
            int ma = wr + t * 16 + lrow;
            int pa = lquad ^ ((ma >> 1) & 3);
            af[t]  = *(const bf16x8_t*)&As[ma * 32 + pa * 8];
            int nb = wc + t * 16 + lrow;
            int pb = lquad ^ ((nb >> 1) & 3);
            bfr[t] = *(const bf16x8_t*)&Bs[nb * 32 + pb * 8];
        }
        #pragma unroll
        for (int mi = 0; mi < 4; ++mi)
            #pragma unroll
            for (int ni = 0; ni < 4; ++ni)
                acc[mi][ni] = __builtin_amdgcn_mfma_f32_16x16x32_bf16(
                    af[mi], bfr[ni], acc[mi][ni], 0, 0, 0);
        __syncthreads();
    }

    // epilogue: D col = lane&15, row = lquad*4 + r  [m89/m91 verified]
    #pragma unroll
    for (int mi = 0; mi < 4; ++mi) {
        #pragma unroll
        for (int ni = 0; ni < 4; ++ni) {
            int col = colBase + wc + ni * 16 + lrow;
            float bv = bias[col];
            #pragma unroll
            for (int r = 0; r < 4; ++r) {
                int row = rowBase + wr + mi * 16 + lquad * 4 + r;
                float v = acc[mi][ni][r] + bv;
                if (res)  v += res[(size_t)row * N + col];
                if (relu) v = fmaxf(v, 0.f);
                if (Cf) Cf[(size_t)row * N + col] = v;
                if (Cb) Cb[(size_t)row * N + col] = f2bf(v);
            }
        }
    }
}

// ---------------------------------------------------------------------------
// fp32 -> bf16 elementwise (n multiple of 4)
// ---------------------------------------------------------------------------
__global__ __launch_bounds__(256)
void conv_bf16(const float* __restrict__ in, ushort_t* __restrict__ out, size_t n)
{
    size_t i = ((size_t)blockIdx.x * 256 + threadIdx.x) * 4;
    if (i >= n) return;
    float4 v = *(const float4*)(in + i);
    out[i + 0] = f2bf(v.x); out[i + 1] = f2bf(v.y);
    out[i + 2] = f2bf(v.z); out[i + 3] = f2bf(v.w);
}

// ---------------------------------------------------------------------------
// Weight transpose+convert: Wt[n][k] = bf16(W[k][n]). K,N multiples of 32.
// ---------------------------------------------------------------------------
__global__ __launch_bounds__(256)
void conv_wt(const float* __restrict__ W, ushort_t* __restrict__ Wt, int K, int N)
{
    __shared__ float t[32][33];
    const int n0 = blockIdx.x * 32, k0 = blockIdx.y * 32;
    const int tx = threadIdx.x, ty = threadIdx.y;   // (32, 8)
    #pragma unroll
    for (int i = 0; i < 4; ++i)
        t[ty * 4 + i][tx] = W[(size_t)(k0 + ty * 4 + i) * N + n0 + tx];
    __syncthreads();
    #pragma unroll
    for (int i = 0; i < 4; ++i)
        Wt[(size_t)(n0 + ty * 4 + i) * K + k0 + tx] = f2bf(t[tx][ty * 4 + i]);
}

// ---------------------------------------------------------------------------
// Build mpi (18432 x 1024 bf16): row b*9+s = memory[b][s] (s<8) else x[b]
// ---------------------------------------------------------------------------
__global__ __launch_bounds__(256)
void build_mpi(const float* __restrict__ mem, const float* __restrict__ x,
               ushort_t* __restrict__ mpi)
{
    size_t i4 = ((size_t)blockIdx.x * 256 + threadIdx.x) * 4;
    if (i4 >= (size_t)18432 * 1024) return;
    int row = (int)(i4 >> 10), col = (int)(i4 & 1023);
    int b = row / 9, s = row - b * 9;
    const float* src = (s < 8) ? (mem + (size_t)b * 8192 + (size_t)s * 1024)
                               : (x + (size_t)b * 1024);
    float4 v = *(const float4*)(src + col);
    mpi[i4 + 0] = f2bf(v.x); mpi[i4 + 1] = f2bf(v.y);
    mpi[i4 + 2] = f2bf(v.z); mpi[i4 + 3] = f2bf(v.w);
}

// ---------------------------------------------------------------------------
// Attention (chunk-local): block per (b,h). qkv bf16 in; writes m1 fp32 + bf16.
// ---------------------------------------------------------------------------
__global__ __launch_bounds__(128)
void attn_kernel(const ushort_t* __restrict__ qkv, const float* __restrict__ mem,
                 float* __restrict__ m1f, ushort_t* __restrict__ m1b)
{
    const int bh = blockIdx.x;
    const int b = bh >> 3, h = bh & 7;
    __shared__ float qs[8][129];
    __shared__ float ks[9][129];
    __shared__ float vs[9][129];
    __shared__ float w[8][9];
    __shared__ float sred[8][9];
    const int tid = threadIdx.x;  // 128
    const float scale = 0.05103103630798288f;  // 384^-0.5

    #pragma unroll
    for (int s = 0; s < 9; ++s) {
        const ushort_t* base = qkv + (size_t)(b * 9 + s) * 3072 + h * 384;
        if (s < 8) qs[s][tid] = bf2f(base[tid]) * scale;
        ks[s][tid] = bf2f(base[128 + tid]);
        vs[s][tid] = bf2f(base[256 + tid]);
    }
    __syncthreads();

    if (tid < 72) {
        const int i = tid / 9, j = tid % 9;
        float sc = 0.f;
        #pragma unroll 8
        for (int d = 0; d < 128; ++d) sc += qs[i][d] * ks[j][d];
        sred[i][j] = sc;
    }
    __syncthreads();

    if (tid < 8) {
        float mx = -1e30f;
        for (int j2 = 0; j2 < 9; ++j2) mx = fmaxf(mx, sred[tid][j2]);
        float e[9], sum = 0.f;
        for (int j2 = 0; j2 < 9; ++j2) { e[j2] = expf(sred[tid][j2] - mx); sum += e[j2]; }
        float inv = 1.f / sum;
        for (int j2 = 0; j2 < 9; ++j2) w[tid][j2] = e[j2] * inv;
    }
    __syncthreads();

    #pragma unroll
    for (int i2 = 0; i2 < 8; ++i2) {
        float acc = 0.f;
        #pragma unroll
        for (int j2 = 0; j2 < 9; ++j2) acc += w[i2][j2] * vs[j2][tid];
        size_t off = (size_t)(b * 8 + i2) * 1024 + (size_t)h * 128 + tid;
        float v = mem[off] + acc;
        m1f[off] = v;
        m1b[off] = f2bf(v);
    }
}

// ---------------------------------------------------------------------------
// gi[b][g] = x[b,:] . kernel_gi[:,g] + bias_gi[g]   (fp32, once)
// ---------------------------------------------------------------------------
__global__ __launch_bounds__(256)
void gi_kernel(const float* __restrict__ x, const float* __restrict__ kgi,
               const float* __restrict__ bgi, float* __restrict__ gi)
{
    const int b = blockIdx.x, tid = threadIdx.x;
    float g0 = 0.f, g1 = 0.f;
    for (int k = tid; k < 1024; k += 256) {
        float xv = x[(size_t)b * 1024 + k];
        g0 += xv * kgi[k * 2];
        g1 += xv * kgi[k * 2 + 1];
    }
    __shared__ float r0[256], r1[256];
    r0[tid] = g0; r1[tid] = g1;
    __syncthreads();
    for (int s = 128; s > 0; s >>= 1) {
        if (tid < s) { r0[tid] += r0[tid + s]; r1[tid] += r1[tid + s]; }
        __syncthreads();
    }
    if (tid == 0) { gi[b * 2] = r0[0] + bgi[0]; gi[b * 2 + 1] = r1[0] + bgi[1]; }
}

// ---------------------------------------------------------------------------
// Final (chunk-local): gm reduction over tanh(mem), sigmoid gates, blend.
// ---------------------------------------------------------------------------
__global__ __launch_bounds__(256)
void final_kernel(const float* __restrict__ mem, const float* __restrict__ m2,
                  const float* __restrict__ kgm, const float* __restrict__ bgm,
                  const float* __restrict__ gi, float* __restrict__ out)
{
    const int row = blockIdx.x;   // chunk-local b*8+s
    const int b = row >> 3;
    const int tid = threadIdx.x;
    const float* mrow = mem + (size_t)row * 1024;
    float g0 = 0.f, g1 = 0.f;
    for (int k = tid; k < 1024; k += 256) {
        float t = tanhf(mrow[k]);
        g0 += t * kgm[k * 2];
        g1 += t * kgm[k * 2 + 1];
    }
    __shared__ float r0[256], r1[256];
    r0[tid] = g0; r1[tid] = g1;
    __syncthreads();
    for (int s = 128; s > 0; s >>= 1) {
        if (tid < s) { r0[tid] += r0[tid + s]; r1[tid] += r1[tid + s]; }
        __syncthreads();
    }
    __shared__ float ig_s, fg_s;
    if (tid == 0) {
        float gate0 = r0[0] + bgm[0] + gi[b * 2];
        float gate1 = r1[0] + bgm[1] + gi[b * 2 + 1] + 1.0f;   // FORGET_BIAS
        ig_s = 1.f / (1.f + expf(-gate0));
        fg_s = 1.f / (1.f + expf(-gate1));
    }
    __syncthreads();
    const float ig = ig_s, fg = fg_s;
    const float* m2row = m2 + (size_t)row * 1024;
    float* orow = out + (size_t)row * 1024;
    for (int k = tid; k < 1024; k += 256)
        orow[k] = ig * tanhf(m2row[k]) + fg * mrow[k];
}

// ---------------------------------------------------------------------------
extern "C" void kernel_launch(void* const* d_in, const int* in_sizes, int n_in,
                              void* d_out, int out_size, void* d_ws, size_t ws_size,
                              hipStream_t stream)
{
    const float* inputs     = (const float*)d_in[0];
    const float* memory     = (const float*)d_in[1];
    const float* kernel_qkv = (const float*)d_in[2];
    const float* bias_qkv   = (const float*)d_in[3];
    const float* kernel_gi  = (const float*)d_in[4];
    const float* bias_gi    = (const float*)d_in[5];
    const float* kernel_gm  = (const float*)d_in[6];
    const float* bias_gm    = (const float*)d_in[7];
    const float* kernel_in  = (const float*)d_in[8];
    const float* bias_in    = (const float*)d_in[9];
    const float* mlp_k0     = (const float*)d_in[10];
    const float* mlp_b0     = (const float*)d_in[11];
    const float* mlp_k1     = (const float*)d_in[12];
    const float* mlp_b1     = (const float*)d_in[13];
    float* out = (float*)d_out;

    // ---- workspace carve (bytes) ----
    char* p = (char*)d_ws;
    float*    ws_x    = (float*)p;     p += (size_t)2048 * 1024 * 4;   // 8 MB
    float*    ws_gi   = (float*)p;     p += (size_t)2048 * 2 * 4;
    ushort_t* in_b    = (ushort_t*)p;  p += (size_t)2048 * 1024 * 2;   // 4 MB
    ushort_t* wt_in   = (ushort_t*)p;  p += (size_t)1024 * 1024 * 2;   // 2 MB
    ushort_t* wt_qkv  = (ushort_t*)p;  p += (size_t)3072 * 1024 * 2;   // 6 MB
    ushort_t* wt_k0   = (ushort_t*)p;  p += (size_t)1024 * 1024 * 2;
    ushort_t* wt_k1   = (ushort_t*)p;  p += (size_t)1024 * 1024 * 2;
    ushort_t* ws_mpi  = (ushort_t*)p;  p += (size_t)18432 * 1024 * 2;  // 36 MB
    size_t fixed = (size_t)(p - (char*)d_ws);

    // per-batch chunk bytes: qkv 9*3072*2 + m1f 8192*4 + m1b 8192*2 + h 8192*2
    const size_t per_batch = 9 * 3072 * 2 + 8192 * 4 + 8192 * 2 + 8192 * 2; // 120832
    int Bc = 128;
    for (int cand = 2048; cand >= 128; cand >>= 1)
        if (fixed + (size_t)cand * per_batch <= ws_size) { Bc = cand; break; }

    ushort_t* ws_qkv = (ushort_t*)p;
    float*    ws_m1f = (float*)((char*)ws_qkv + (size_t)Bc * 9 * 3072 * 2);
    ushort_t* ws_m1b = (ushort_t*)((char*)ws_m1f + (size_t)Bc * 8192 * 4);
    ushort_t* ws_h   = (ushort_t*)((char*)ws_m1b + (size_t)Bc * 8192 * 2);

    // ---- one-time conversions ----
    conv_bf16<<<2048, 256, 0, stream>>>(inputs, in_b, (size_t)2048 * 1024);
    dim3 wtb(32, 8);
    conv_wt<<<dim3(32, 32), wtb, 0, stream>>>(kernel_in, wt_in, 1024, 1024);
    conv_wt<<<dim3(96, 32), wtb, 0, stream>>>(kernel_qkv, wt_qkv, 1024, 3072);
    conv_wt<<<dim3(32, 32), wtb, 0, stream>>>(mlp_k0, wt_k0, 1024, 1024);
    conv_wt<<<dim3(32, 32), wtb, 0, stream>>>(mlp_k1, wt_k1, 1024, 1024);

    // x = inputs @ kernel_in + bias_in   (2048x1024, fp32 out)
    gemm_mfma<<<dim3(1024 / 128, 2048 / 128), 256, 0, stream>>>(
        in_b, wt_in, bias_in, ws_x, nullptr, nullptr, 2048, 1024, 1024, 0);

    gi_kernel<<<2048, 256, 0, stream>>>(ws_x, kernel_gi, bias_gi, ws_gi);
    build_mpi<<<18432, 256, 0, stream>>>(memory, ws_x, ws_mpi);

    const int NC = 2048 / Bc;
    for (int c = 0; c < NC; ++c) {
        const int b0 = c * Bc;
        const float*    mem_c = memory + (size_t)b0 * 8192;
        const ushort_t* mpi_c = ws_mpi + (size_t)b0 * 9 * 1024;

        // qkv = mpi @ kernel_qkv + bias_qkv   (Bc*9 x 3072, bf16 out)
        gemm_mfma<<<dim3(3072 / 128, Bc * 9 / 128), 256, 0, stream>>>(
            mpi_c, wt_qkv, bias_qkv, nullptr, ws_qkv, nullptr, Bc * 9, 3072, 1024, 0);

        attn_kernel<<<Bc * 8, 128, 0, stream>>>(ws_qkv, mem_c, ws_m1f, ws_m1b);

        // h = relu(m1 @ mlp_k0 + mlp_b0)   (bf16 out)
        gemm_mfma<<<dim3(1024 / 128, Bc * 8 / 128), 256, 0, stream>>>(
            ws_m1b, wt_k0, mlp_b0, nullptr, ws_h, nullptr, Bc * 8, 1024, 1024, 1);

        // m2 = m1 + h @ mlp_k1 + mlp_b1   (fp32, in-place over m1f)
        gemm_mfma<<<dim3(1024 / 128, Bc * 8 / 128), 256, 0, stream>>>(
            ws_h, wt_k1, mlp_b1, ws_m1f, nullptr, ws_m1f, Bc * 8, 1024, 1024, 0);

        final_kernel<<<Bc * 8, 256, 0, stream>>>(
            mem_c, ws_m1f, kernel_gm, bias_gm, ws_gi + (size_t)b0 * 2,
            out + (size_t)b0 * 8192);
    }
}